// Round 9
// baseline (91.362 us; speedup 1.0000x reference)
//
#include <hip/hip_runtime.h>

// SpatialAttention: B=4 T=12 N=512 D=128, 8 heads x d=16.
// wprep_k (weight transpose->bf16, 128 blocks) -> qkv_k (f32-direct LDS-free GEMM,
// in-reg bf16 cvt) -> attn_k (R5-validated flash, FROZEN) -> oproj_k (R5 128-row).

typedef unsigned short u16;
typedef unsigned int u32;
typedef __bf16 bf16_t;
typedef bf16_t bf16x8 __attribute__((ext_vector_type(8)));
typedef float f32x4 __attribute__((ext_vector_type(4)));
typedef u16 u16x8 __attribute__((ext_vector_type(8)));
typedef u16 u16x4 __attribute__((ext_vector_type(4)));
typedef u32 u32x2 __attribute__((ext_vector_type(2)));
typedef u32 u32x4 __attribute__((ext_vector_type(4)));

__device__ __forceinline__ u16 f2bf(float f) {
    unsigned u = __builtin_bit_cast(unsigned, f);
    u += 0x7FFFu + ((u >> 16) & 1u);   // round-to-nearest-even
    return (u16)(u >> 16);
}

__device__ __forceinline__ f32x4 mfma16(bf16x8 a, bf16x8 b, f32x4 c) {
    return __builtin_amdgcn_mfma_f32_16x16x32_bf16(a, b, c, 0, 0, 0);
}

__device__ __forceinline__ u32 cvt_pk_bf16(float lo, float hi) {
    u32 w;
    asm("v_cvt_pk_bf16_f32 %0, %1, %2" : "=v"(w) : "v"(lo), "v"(hi));
    return w;
}

// load 8 consecutive f32 and pack to bf16x8 (RNE, same as f2bf)
__device__ __forceinline__ bf16x8 load_f32x8_as_bf16(const float* p) {
    f32x4 a = *(const f32x4*)p;
    f32x4 b = *(const f32x4*)(p + 4);
    u32x4 w;
    w[0] = cvt_pk_bf16(a[0], a[1]);
    w[1] = cvt_pk_bf16(a[2], a[3]);
    w[2] = cvt_pk_bf16(b[0], b[1]);
    w[3] = cvt_pk_bf16(b[2], b[3]);
    return __builtin_bit_cast(bf16x8, w);
}

// ---------------------------------------------------------------------------
// Weight transpose+convert only: wt[3][128][256] (QKV), wto[2][128][128]. 128 blocks.
// ---------------------------------------------------------------------------
__global__ __launch_bounds__(256) void wprep_k(const float* __restrict__ Wq,
                                               const float* __restrict__ Wk,
                                               const float* __restrict__ Wv,
                                               const float* __restrict__ Wo1,
                                               const float* __restrict__ Wo2,
                                               u16* __restrict__ wtq,
                                               u16* __restrict__ wto1)
{
    const int wb = blockIdx.x, tid = threadIdx.x;
    const float* src; u16* dst; int K, lb;
    if (wb < 96) { int m = wb >> 5; src = (m == 0) ? Wq : (m == 1) ? Wk : Wv;
                   dst = wtq + m * 32768; K = 256; lb = wb & 31; }
    else         { int m = (wb - 96) >> 4; src = (m == 0) ? Wo1 : Wo2;
                   dst = wto1 + m * 16384; K = 128; lb = (wb - 96) & 15; }
    int pos = lb * 256 + tid;
    f32x4 v = *(const f32x4*)(src + (long)pos * 4);
    int k  = pos >> 5;
    int n0 = (pos * 4) & 127;
#pragma unroll
    for (int j = 0; j < 4; ++j) dst[(n0 + j) * K + k] = f2bf(v[j]);
}

// ---------------------------------------------------------------------------
// LDS-free QKV projection, swapped operands: D[feature][token].
// A (tokens) read DIRECT from f32 x/ste with in-register bf16 conversion —
// no xc intermediate. Grid (192,3): y=0 Q(scaled), y=1 K, y=2 V(V^T out).
// ---------------------------------------------------------------------------
__global__ __launch_bounds__(256) void qkv_k(const float* __restrict__ x,
                                             const float* __restrict__ ste,
                                             const u16* __restrict__ wt,
                                             const float* __restrict__ bq,
                                             const float* __restrict__ bk,
                                             const float* __restrict__ bv,
                                             u16* __restrict__ qbuf,
                                             u16* __restrict__ kbuf,
                                             u16* __restrict__ vbuf,
                                             float qscale)
{
    const int y = blockIdx.y;
    const u16* WT     = wt + y * 32768;                 // [128 feat][256 k]
    const float* bias = (y == 0) ? bq : (y == 1) ? bk : bv;
    u16* Out          = (y == 0) ? qbuf : (y == 1) ? kbuf : vbuf;
    const float scale = (y == 0) ? qscale : 1.0f;

    const int tid  = threadIdx.x;
    const int wave = tid >> 6;
    const int lane = tid & 63;
    const int g    = lane >> 4;
    const int lc   = lane & 15;
    const int wr   = wave >> 1;
    const int wc   = wave & 1;
    const long mbase = (long)blockIdx.x * 128;

    const long arow0 = (mbase + wr * 64 + lc) * 128;       // f32 row base (D=128 per src)
    const u16* brow  = WT + (wc * 64 + lc) * 256;          // feature frags (A operand)

    const f32x4 ZERO4 = {0.f, 0.f, 0.f, 0.f};
    f32x4 acc[4][4];   // [token tile m][feature tile n]; regs r = feat g*4+r, lane lc = token
#pragma unroll
    for (int m = 0; m < 4; ++m)
#pragma unroll
        for (int n = 0; n < 4; ++n) acc[m][n] = ZERO4;

#pragma unroll 2
    for (int k0 = 0; k0 < 256; k0 += 32) {
        const float* asrc = (k0 < 128) ? x : ste;
        const int kk = k0 & 127;
        bf16x8 tf[4], wf[4];
#pragma unroll
        for (int m = 0; m < 4; ++m)
            tf[m] = load_f32x8_as_bf16(asrc + arow0 + m * 2048 + kk + g * 8);
#pragma unroll
        for (int n = 0; n < 4; ++n)
            wf[n] = *(const bf16x8*)(brow + n * 4096 + k0 + g * 8);
#pragma unroll
        for (int m = 0; m < 4; ++m)
#pragma unroll
            for (int n = 0; n < 4; ++n)
                acc[m][n] = mfma16(wf[n], tf[m], acc[m][n]);   // D[feat][tok]
    }

#pragma unroll
    for (int m = 0; m < 4; ++m) {
        const long tok = mbase + wr * 64 + m * 16 + lc;
        const long bt = tok >> 9;
        const long nn = tok & 511;
#pragma unroll
        for (int n = 0; n < 4; ++n) {
            const int feat0 = wc * 64 + n * 16 + g * 4;
            const int head  = feat0 >> 4;
            const int d0    = feat0 & 15;
            f32x4 b4 = *(const f32x4*)(bias + feat0);
            if (y == 2) {          // V^T: [head][16][512]
#pragma unroll
                for (int r = 0; r < 4; ++r) {
                    float v = fmaxf(acc[m][n][r] + b4[r], 0.f);
                    Out[((bt * 8 + head) * 16 + d0 + r) * 512 + nn] = f2bf(v);
                }
            } else {               // Q/K: [head][512][16], u16x4 fully coalesced
                u16x4 pk;
#pragma unroll
                for (int r = 0; r < 4; ++r)
                    pk[r] = f2bf(fmaxf(acc[m][n][r] + b4[r], 0.f) * scale);
                *(u16x4*)&Out[((bt * 8 + head) * 512 + nn) * 16 + d0] = pk;
            }
        }
    }
}

// ---------------------------------------------------------------------------
// Flash attention — R5-VALIDATED VERSION, FROZEN (passed 3/3). Swapped QK^T
// (S^T=mfma(K,Q)), lane owns one q-row; defer-max (THR=8 log2); cvt_pk P-pack;
// single per-wave Ps buffer; Ks+Vt staged in LDS. Grid (2,8,48), 4 waves.
// ---------------------------------------------------------------------------
__global__ __launch_bounds__(256) void attn_k(const u16* __restrict__ qb,
                                              const u16* __restrict__ kb,
                                              const u16* __restrict__ vtb,
                                              u16* __restrict__ ob)
{
    __shared__ u16 smem[25216];
    u16 (*Ks)[24]     = reinterpret_cast<u16(*)[24]>(smem);
    u16 (*Vt)[520]    = reinterpret_cast<u16(*)[520]>(smem + 12288);
    u16 (*Ps)[16][72] = reinterpret_cast<u16(*)[16][72]>(smem + 12288 + 8320);

    const int tid  = threadIdx.x;
    const int wave = tid >> 6;
    const int lane = tid & 63;
    const int g    = lane >> 4;
    const int lc   = lane & 15;
    const int qt = blockIdx.x, h = blockIdx.y, bt = blockIdx.z;
    const long hb = ((long)(bt * 8 + h)) * 8192;

    const u16x8 ZU8 = {0, 0, 0, 0, 0, 0, 0, 0};
    const bf16x8 zf = __builtin_bit_cast(bf16x8, ZU8);
    const f32x4 ZERO4 = {0.f, 0.f, 0.f, 0.f};

    // stage K [512][16]
#pragma unroll
    for (int i = 0; i < 4; ++i) {
        int pos = tid + i * 256;
        int row = pos >> 1, half = pos & 1;
        *(u16x8*)&Ks[row][half * 8] = *(const u16x8*)(kb + hb + row * 16 + half * 8);
    }
    // stage V^T [16][512]
#pragma unroll
    for (int i = 0; i < 4; ++i) {
        int pos = tid + i * 256;
        int r16 = pos >> 6, c8 = pos & 63;
        *(u16x8*)&Vt[r16][c8 * 8] = *(const u16x8*)(vtb + hb + r16 * 512 + c8 * 8);
    }

    const int qrow0 = qt * 256 + wave * 64;
    bf16x8 qf[4];
#pragma unroll
    for (int mt = 0; mt < 4; ++mt)
        qf[mt] = (g < 2) ? *(const bf16x8*)(qb + hb + (qrow0 + mt * 16 + lc) * 16 + g * 8) : zf;

    // per-lane state for q-row = (mt*16 + lc)
    float m_s[4], l_s[4];
    f32x4 oacc[4];
#pragma unroll
    for (int mt = 0; mt < 4; ++mt) { m_s[mt] = -1e30f; l_s[mt] = 0.f; oacc[mt] = ZERO4; }

    const int bcast = (lane & 48) + ((lane & 48) >> 2);   // src lane base for row g*4+r values

    __syncthreads();   // the only block-wide barrier

    for (int ch = 0; ch < 8; ++ch) {
        bf16x8 kf[4];
#pragma unroll
        for (int nt = 0; nt < 4; ++nt)
            kf[nt] = (g < 2) ? *(const bf16x8*)&Ks[ch * 64 + nt * 16 + lc][g * 8] : zf;

#pragma unroll
        for (int mt = 0; mt < 4; ++mt) {
            // S^T tiles: lane (lc,g) holds S[q=lc][key = ch*64 + nt*16 + g*4 + r]
            f32x4 st[4];
#pragma unroll
            for (int nt = 0; nt < 4; ++nt) st[nt] = mfma16(kf[nt], qf[mt], ZERO4);

            float mx = st[0][0];
#pragma unroll
            for (int nt = 0; nt < 4; ++nt)
#pragma unroll
                for (int r = 0; r < 4; ++r) mx = fmaxf(mx, st[nt][r]);
            mx = fmaxf(mx, __shfl_xor(mx, 16));
            mx = fmaxf(mx, __shfl_xor(mx, 32));

            float m0 = m_s[mt];
            if (__any(mx > m0 + 8.f)) {          // rescale path (rare after ch 0)
                float mnew = fmaxf(m0, mx);
                float alpha = __builtin_amdgcn_exp2f(m0 - mnew);
                f32x4 av;
#pragma unroll
                for (int r = 0; r < 4; ++r) av[r] = __shfl(alpha, bcast + r);
                oacc[mt] *= av;
                l_s[mt] *= alpha;
                m_s[mt] = mnew;
            }
            const float mm = m_s[mt];
            float rs = 0.f;
#pragma unroll
            for (int nt = 0; nt < 4; ++nt)
#pragma unroll
                for (int r = 0; r < 4; ++r) {
                    float p = __builtin_amdgcn_exp2f(st[nt][r] - mm);
                    st[nt][r] = p;
                    rs += p;
                }
            rs += __shfl_xor(rs, 16);
            rs += __shfl_xor(rs, 32);
            l_s[mt] += rs;

            // pack P -> bf16 pairs, b64 writes: Ps[wave][q=lc][key]
#pragma unroll
            for (int nt = 0; nt < 4; ++nt) {
                u32x2 w;
                w[0] = cvt_pk_bf16(st[nt][0], st[nt][1]);
                w[1] = cvt_pk_bf16(st[nt][2], st[nt][3]);
                *(u32x2*)&Ps[wave][lc][nt * 16 + g * 4] = w;
            }
            // O += P V
#pragma unroll
            for (int ks = 0; ks < 2; ++ks) {
                bf16x8 pf = *(const bf16x8*)&Ps[wave][lc][ks * 32 + g * 8];
                bf16x8 vf = *(const bf16x8*)&Vt[lc][ch * 64 + ks * 32 + g * 8];
                oacc[mt] = mfma16(pf, vf, oacc[mt]);
            }
        }
    }

    // write O [24576][128]; l for q-row g*4+r via shfl
#pragma unroll
    for (int mt = 0; mt < 4; ++mt)
#pragma unroll
        for (int r = 0; r < 4; ++r) {
            float lr = __shfl(l_s[mt], bcast + r);
            int row = qrow0 + mt * 16 + g * 4 + r;
            float rl = __builtin_amdgcn_rcpf(lr);
            ob[((long)bt * 512 + row) * 128 + h * 16 + lc] = f2bf(oacc[mt][r] * rl);
        }
}

// ---------------------------------------------------------------------------
// Fused output projections — R5-VALIDATED 128-row version. Swapped operands,
// B-frags direct from global, h in LDS. Grid 192, 4 waves x (64tok x 64feat).
// ---------------------------------------------------------------------------
__global__ __launch_bounds__(256) void oproj_k(const u16* __restrict__ O,
                                               const u16* __restrict__ wt1,
                                               const float* __restrict__ b1,
                                               const u16* __restrict__ wt2,
                                               const float* __restrict__ b2,
                                               float* __restrict__ out)
{
    __shared__ u16 Hs[128][136];   // [token][feature]

    const int tid  = threadIdx.x;
    const int wave = tid >> 6;
    const int lane = tid & 63;
    const int g    = lane >> 4;
    const int lc   = lane & 15;
    const int wr   = wave >> 1;
    const int wc   = wave & 1;
    const long mbase = (long)blockIdx.x * 128;

    const f32x4 ZERO4 = {0.f, 0.f, 0.f, 0.f};
    f32x4 acc[4][4];
#pragma unroll
    for (int m = 0; m < 4; ++m)
#pragma unroll
        for (int n = 0; n < 4; ++n) acc[m][n] = ZERO4;

    const u16* arow  = O   + (mbase + wr * 64 + lc) * 128;   // token frags
    const u16* b1row = wt1 + (wc * 64 + lc) * 128;           // feature frags
    const u16* b2row = wt2 + (wc * 64 + lc) * 128;

    // stage 1: h = relu(O*W1 + b1) -> Hs[tok][feat]
#pragma unroll 2
    for (int k0 = 0; k0 < 128; k0 += 32) {
        bf16x8 tf[4], wf[4];
#pragma unroll
        for (int m = 0; m < 4; ++m)
            tf[m] = *(const bf16x8*)(arow + m * 2048 + k0 + g * 8);
#pragma unroll
        for (int n = 0; n < 4; ++n)
            wf[n] = *(const bf16x8*)(b1row + n * 2048 + k0 + g * 8);
#pragma unroll
        for (int m = 0; m < 4; ++m)
#pragma unroll
            for (int n = 0; n < 4; ++n)
                acc[m][n] = mfma16(wf[n], tf[m], acc[m][n]);
    }
#pragma unroll
    for (int m = 0; m < 4; ++m) {
        const int tok = wr * 64 + m * 16 + lc;
#pragma unroll
        for (int n = 0; n < 4; ++n) {
            const int feat0 = wc * 64 + n * 16 + g * 4;
            f32x4 b4 = *(const f32x4*)(b1 + feat0);
            u16x4 pk;
#pragma unroll
            for (int r = 0; r < 4; ++r)
                pk[r] = f2bf(fmaxf(acc[m][n][r] + b4[r], 0.f));
            *(u16x4*)&Hs[tok][feat0] = pk;
            acc[m][n] = ZERO4;
        }
    }
    __syncthreads();

    // stage 2: out = h*W2 + b2
#pragma unroll 2
    for (int k0 = 0; k0 < 128; k0 += 32) {
        bf16x8 tf[4], wf[4];
#pragma unroll
        for (int m = 0; m < 4; ++m)
            tf[m] = *(const bf16x8*)&Hs[wr * 64 + m * 16 + lc][k0 + g * 8];
#pragma unroll
        for (int n = 0; n < 4; ++n)
            wf[n] = *(const bf16x8*)(b2row + n * 2048 + k0 + g * 8);
#pragma unroll
        for (int m = 0; m < 4; ++m)
#pragma unroll
            for (int n = 0; n < 4; ++n)
                acc[m][n] = mfma16(wf[n], tf[m], acc[m][n]);
    }
#pragma unroll
    for (int m = 0; m < 4; ++m) {
        const long tok = mbase + wr * 64 + m * 16 + lc;
#pragma unroll
        for (int n = 0; n < 4; ++n) {
            const int feat0 = wc * 64 + n * 16 + g * 4;
            f32x4 b4 = *(const f32x4*)(b2 + feat0);
            f32x4 v;
#pragma unroll
            for (int r = 0; r < 4; ++r) v[r] = acc[m][n][r] + b4[r];
            *(f32x4*)&out[tok * 128 + feat0] = v;
        }
    }
}

extern "C" void kernel_launch(void* const* d_in, const int* in_sizes, int n_in,
                              void* d_out, int out_size, void* d_ws, size_t ws_size,
                              hipStream_t stream)
{
    const float* x   = (const float*)d_in[0];
    const float* ste = (const float*)d_in[1];
    const float* Wq  = (const float*)d_in[2];
    const float* bq  = (const float*)d_in[3];
    const float* Wk  = (const float*)d_in[4];
    const float* bk  = (const float*)d_in[5];
    const float* Wv  = (const float*)d_in[6];
    const float* bv  = (const float*)d_in[7];
    const float* Wo1 = (const float*)d_in[8];
    const float* bo1 = (const float*)d_in[9];
    const float* Wo2 = (const float*)d_in[10];
    const float* bo2 = (const float*)d_in[11];
    float* out = (float*)d_out;

    const long MTOT = 24576;
    u16* qbuf = (u16*)d_ws;                  // [384][512][16]
    u16* kbuf = qbuf + MTOT * 128;
    u16* vbuf = kbuf + MTOT * 128;           // V^T [384][16][512]
    u16* obuf = vbuf + MTOT * 128;           // O merged [24576][128]
    u16* wtq  = obuf + MTOT * 128;           // W^T bf16: [3][128][256]
    u16* wto1 = wtq + 3 * 32768;             // [2][128][128]

    const float QSCALE = 0.25f * 1.44269504f;   // 1/sqrt(16) * log2(e)

    dim3 blk(256);
    wprep_k<<<dim3(128), blk, 0, stream>>>(Wq, Wk, Wv, Wo1, Wo2, wtq, wto1);
    qkv_k<<<dim3(192, 3), blk, 0, stream>>>(x, ste, wtq, bq, bk, bv, qbuf, kbuf, vbuf, QSCALE);
    attn_k<<<dim3(2, 8, 48), blk, 0, stream>>>(qbuf, kbuf, vbuf, obuf);
    oproj_k<<<dim3(192), blk, 0, stream>>>(obuf, wto1, bo1, wto1 + 16384, bo2, out);
}

// Round 10
// 84.982 us; speedup vs baseline: 1.0751x; 1.0751x over previous
//
#include <hip/hip_runtime.h>

// SpatialAttention: B=4 T=12 N=512 D=128, 8 heads x d=16.
// R5-champion pipeline: cvt_k (concat->bf16 u16x8 + weight transpose) ->
// qkv_k (LDS-free swapped GEMM from xc) -> attn_k (R5 flash, FROZEN) ->
// oproj_k (fused 2-stage, 128-row).

typedef unsigned short u16;
typedef unsigned int u32;
typedef __bf16 bf16_t;
typedef bf16_t bf16x8 __attribute__((ext_vector_type(8)));
typedef float f32x4 __attribute__((ext_vector_type(4)));
typedef u16 u16x8 __attribute__((ext_vector_type(8)));
typedef u16 u16x4 __attribute__((ext_vector_type(4)));
typedef u32 u32x2 __attribute__((ext_vector_type(2)));
typedef u32 u32x4 __attribute__((ext_vector_type(4)));

__device__ __forceinline__ u16 f2bf(float f) {
    unsigned u = __builtin_bit_cast(unsigned, f);
    u += 0x7FFFu + ((u >> 16) & 1u);   // round-to-nearest-even
    return (u16)(u >> 16);
}

__device__ __forceinline__ f32x4 mfma16(bf16x8 a, bf16x8 b, f32x4 c) {
    return __builtin_amdgcn_mfma_f32_16x16x32_bf16(a, b, c, 0, 0, 0);
}

__device__ __forceinline__ u32 cvt_pk_bf16(float lo, float hi) {
    u32 w;
    asm("v_cvt_pk_bf16_f32 %0, %1, %2" : "=v"(w) : "v"(lo), "v"(hi));
    return w;
}

// load 8 consecutive f32, pack to 8 bf16 (RNE)
__device__ __forceinline__ u16x8 pack_f32x8(const float* p) {
    f32x4 a = *(const f32x4*)p;
    f32x4 b = *(const f32x4*)(p + 4);
    u32x4 w;
    w[0] = cvt_pk_bf16(a[0], a[1]);
    w[1] = cvt_pk_bf16(a[2], a[3]);
    w[2] = cvt_pk_bf16(b[0], b[1]);
    w[3] = cvt_pk_bf16(b[2], b[3]);
    return __builtin_bit_cast(u16x8, w);
}

// ---------------------------------------------------------------------------
// Blocks 0..1535: xc[24576][256] = [bf16(x) | bf16(ste)], 8 elems/thread/src
// Blocks 1536..1663: weight transpose+convert: wt[3][128][256], wto[2][128][128]
// ---------------------------------------------------------------------------
__global__ __launch_bounds__(256) void cvt_k(const float* __restrict__ x,
                                             const float* __restrict__ ste,
                                             const float* __restrict__ Wq,
                                             const float* __restrict__ Wk,
                                             const float* __restrict__ Wv,
                                             const float* __restrict__ Wo1,
                                             const float* __restrict__ Wo2,
                                             u16* __restrict__ xc,
                                             u16* __restrict__ wtq,
                                             u16* __restrict__ wto1)
{
    const int b = blockIdx.x, tid = threadIdx.x;
    if (b < 1536) {
        long idx = (long)b * 256 + tid;          // 0..393215, 8 elems per src
        long row = idx >> 4; int c = (int)(idx & 15);
        *(u16x8*)(xc + row * 256 + c * 8)       = pack_f32x8(x + idx * 8);
        *(u16x8*)(xc + row * 256 + 128 + c * 8) = pack_f32x8(ste + idx * 8);
    } else {
        int wb = b - 1536;
        const float* src; u16* dst; int K, lb;
        if (wb < 96) { int m = wb >> 5; src = (m == 0) ? Wq : (m == 1) ? Wk : Wv;
                       dst = wtq + m * 32768; K = 256; lb = wb & 31; }
        else         { int m = (wb - 96) >> 4; src = (m == 0) ? Wo1 : Wo2;
                       dst = wto1 + m * 16384; K = 128; lb = (wb - 96) & 15; }
        int pos = lb * 256 + tid;
        f32x4 v = *(const f32x4*)(src + (long)pos * 4);
        int k  = pos >> 5;
        int n0 = (pos * 4) & 127;
#pragma unroll
        for (int j = 0; j < 4; ++j) dst[(n0 + j) * K + k] = f2bf(v[j]);
    }
}

// ---------------------------------------------------------------------------
// LDS-free QKV projection, swapped operands: D[feature][token]. From xc (bf16).
// Grid (192,3): y=0 Q(scaled), y=1 K, y=2 V(V^T out). No LDS, no barriers.
// ---------------------------------------------------------------------------
__global__ __launch_bounds__(256) void qkv_k(const u16* __restrict__ xc,
                                             const u16* __restrict__ wt,
                                             const float* __restrict__ bq,
                                             const float* __restrict__ bk,
                                             const float* __restrict__ bv,
                                             u16* __restrict__ qbuf,
                                             u16* __restrict__ kbuf,
                                             u16* __restrict__ vbuf,
                                             float qscale)
{
    const int y = blockIdx.y;
    const u16* WT     = wt + y * 32768;                 // [128 feat][256 k]
    const float* bias = (y == 0) ? bq : (y == 1) ? bk : bv;
    u16* Out          = (y == 0) ? qbuf : (y == 1) ? kbuf : vbuf;
    const float scale = (y == 0) ? qscale : 1.0f;

    const int tid  = threadIdx.x;
    const int wave = tid >> 6;
    const int lane = tid & 63;
    const int g    = lane >> 4;
    const int lc   = lane & 15;
    const int wr   = wave >> 1;
    const int wc   = wave & 1;
    const long mbase = (long)blockIdx.x * 128;

    const u16* arow = xc + (mbase + wr * 64 + lc) * 256;   // token frags (B operand)
    const u16* brow = WT + (wc * 64 + lc) * 256;           // feature frags (A operand)

    const f32x4 ZERO4 = {0.f, 0.f, 0.f, 0.f};
    f32x4 acc[4][4];
#pragma unroll
    for (int m = 0; m < 4; ++m)
#pragma unroll
        for (int n = 0; n < 4; ++n) acc[m][n] = ZERO4;

#pragma unroll 2
    for (int k0 = 0; k0 < 256; k0 += 32) {
        bf16x8 tf[4], wf[4];
#pragma unroll
        for (int m = 0; m < 4; ++m)
            tf[m] = *(const bf16x8*)(arow + m * 4096 + k0 + g * 8);
#pragma unroll
        for (int n = 0; n < 4; ++n)
            wf[n] = *(const bf16x8*)(brow + n * 4096 + k0 + g * 8);
#pragma unroll
        for (int m = 0; m < 4; ++m)
#pragma unroll
            for (int n = 0; n < 4; ++n)
                acc[m][n] = mfma16(wf[n], tf[m], acc[m][n]);   // D[feat][tok]
    }

#pragma unroll
    for (int m = 0; m < 4; ++m) {
        const long tok = mbase + wr * 64 + m * 16 + lc;
        const long bt = tok >> 9;
        const long nn = tok & 511;
#pragma unroll
        for (int n = 0; n < 4; ++n) {
            const int feat0 = wc * 64 + n * 16 + g * 4;
            const int head  = feat0 >> 4;
            const int d0    = feat0 & 15;
            f32x4 b4 = *(const f32x4*)(bias + feat0);
            if (y == 2) {          // V^T: [head][16][512]
#pragma unroll
                for (int r = 0; r < 4; ++r) {
                    float v = fmaxf(acc[m][n][r] + b4[r], 0.f);
                    Out[((bt * 8 + head) * 16 + d0 + r) * 512 + nn] = f2bf(v);
                }
            } else {               // Q/K: [head][512][16], u16x4 fully coalesced
                u16x4 pk;
#pragma unroll
                for (int r = 0; r < 4; ++r)
                    pk[r] = f2bf(fmaxf(acc[m][n][r] + b4[r], 0.f) * scale);
                *(u16x4*)&Out[((bt * 8 + head) * 512 + nn) * 16 + d0] = pk;
            }
        }
    }
}

// ---------------------------------------------------------------------------
// Flash attention — R5-VALIDATED VERSION, FROZEN (passed 4/4). Swapped QK^T
// (S^T=mfma(K,Q)), lane owns one q-row; defer-max (THR=8 log2); cvt_pk P-pack;
// single per-wave Ps buffer; Ks+Vt staged in LDS. Grid (2,8,48), 4 waves.
// ---------------------------------------------------------------------------
__global__ __launch_bounds__(256) void attn_k(const u16* __restrict__ qb,
                                              const u16* __restrict__ kb,
                                              const u16* __restrict__ vtb,
                                              u16* __restrict__ ob)
{
    __shared__ u16 smem[25216];
    u16 (*Ks)[24]     = reinterpret_cast<u16(*)[24]>(smem);
    u16 (*Vt)[520]    = reinterpret_cast<u16(*)[520]>(smem + 12288);
    u16 (*Ps)[16][72] = reinterpret_cast<u16(*)[16][72]>(smem + 12288 + 8320);

    const int tid  = threadIdx.x;
    const int wave = tid >> 6;
    const int lane = tid & 63;
    const int g    = lane >> 4;
    const int lc   = lane & 15;
    const int qt = blockIdx.x, h = blockIdx.y, bt = blockIdx.z;
    const long hb = ((long)(bt * 8 + h)) * 8192;

    const u16x8 ZU8 = {0, 0, 0, 0, 0, 0, 0, 0};
    const bf16x8 zf = __builtin_bit_cast(bf16x8, ZU8);
    const f32x4 ZERO4 = {0.f, 0.f, 0.f, 0.f};

    // stage K [512][16]
#pragma unroll
    for (int i = 0; i < 4; ++i) {
        int pos = tid + i * 256;
        int row = pos >> 1, half = pos & 1;
        *(u16x8*)&Ks[row][half * 8] = *(const u16x8*)(kb + hb + row * 16 + half * 8);
    }
    // stage V^T [16][512]
#pragma unroll
    for (int i = 0; i < 4; ++i) {
        int pos = tid + i * 256;
        int r16 = pos >> 6, c8 = pos & 63;
        *(u16x8*)&Vt[r16][c8 * 8] = *(const u16x8*)(vtb + hb + r16 * 512 + c8 * 8);
    }

    const int qrow0 = qt * 256 + wave * 64;
    bf16x8 qf[4];
#pragma unroll
    for (int mt = 0; mt < 4; ++mt)
        qf[mt] = (g < 2) ? *(const bf16x8*)(qb + hb + (qrow0 + mt * 16 + lc) * 16 + g * 8) : zf;

    // per-lane state for q-row = (mt*16 + lc)
    float m_s[4], l_s[4];
    f32x4 oacc[4];
#pragma unroll
    for (int mt = 0; mt < 4; ++mt) { m_s[mt] = -1e30f; l_s[mt] = 0.f; oacc[mt] = ZERO4; }

    const int bcast = (lane & 48) + ((lane & 48) >> 2);   // src lane base for row g*4+r values

    __syncthreads();   // the only block-wide barrier

    for (int ch = 0; ch < 8; ++ch) {
        bf16x8 kf[4];
#pragma unroll
        for (int nt = 0; nt < 4; ++nt)
            kf[nt] = (g < 2) ? *(const bf16x8*)&Ks[ch * 64 + nt * 16 + lc][g * 8] : zf;

#pragma unroll
        for (int mt = 0; mt < 4; ++mt) {
            // S^T tiles: lane (lc,g) holds S[q=lc][key = ch*64 + nt*16 + g*4 + r]
            f32x4 st[4];
#pragma unroll
            for (int nt = 0; nt < 4; ++nt) st[nt] = mfma16(kf[nt], qf[mt], ZERO4);

            float mx = st[0][0];
#pragma unroll
            for (int nt = 0; nt < 4; ++nt)
#pragma unroll
                for (int r = 0; r < 4; ++r) mx = fmaxf(mx, st[nt][r]);
            mx = fmaxf(mx, __shfl_xor(mx, 16));
            mx = fmaxf(mx, __shfl_xor(mx, 32));

            float m0 = m_s[mt];
            if (__any(mx > m0 + 8.f)) {          // rescale path (rare after ch 0)
                float mnew = fmaxf(m0, mx);
                float alpha = __builtin_amdgcn_exp2f(m0 - mnew);
                f32x4 av;
#pragma unroll
                for (int r = 0; r < 4; ++r) av[r] = __shfl(alpha, bcast + r);
                oacc[mt] *= av;
                l_s[mt] *= alpha;
                m_s[mt] = mnew;
            }
            const float mm = m_s[mt];
            float rs = 0.f;
#pragma unroll
            for (int nt = 0; nt < 4; ++nt)
#pragma unroll
                for (int r = 0; r < 4; ++r) {
                    float p = __builtin_amdgcn_exp2f(st[nt][r] - mm);
                    st[nt][r] = p;
                    rs += p;
                }
            rs += __shfl_xor(rs, 16);
            rs += __shfl_xor(rs, 32);
            l_s[mt] += rs;

            // pack P -> bf16 pairs, b64 writes: Ps[wave][q=lc][key]
#pragma unroll
            for (int nt = 0; nt < 4; ++nt) {
                u32x2 w;
                w[0] = cvt_pk_bf16(st[nt][0], st[nt][1]);
                w[1] = cvt_pk_bf16(st[nt][2], st[nt][3]);
                *(u32x2*)&Ps[wave][lc][nt * 16 + g * 4] = w;
            }
            // O += P V
#pragma unroll
            for (int ks = 0; ks < 2; ++ks) {
                bf16x8 pf = *(const bf16x8*)&Ps[wave][lc][ks * 32 + g * 8];
                bf16x8 vf = *(const bf16x8*)&Vt[lc][ch * 64 + ks * 32 + g * 8];
                oacc[mt] = mfma16(pf, vf, oacc[mt]);
            }
        }
    }

    // write O [24576][128]; l for q-row g*4+r via shfl
#pragma unroll
    for (int mt = 0; mt < 4; ++mt)
#pragma unroll
        for (int r = 0; r < 4; ++r) {
            float lr = __shfl(l_s[mt], bcast + r);
            int row = qrow0 + mt * 16 + g * 4 + r;
            float rl = __builtin_amdgcn_rcpf(lr);
            ob[((long)bt * 512 + row) * 128 + h * 16 + lc] = f2bf(oacc[mt][r] * rl);
        }
}

// ---------------------------------------------------------------------------
// Fused output projections — R5-VALIDATED 128-row version. Swapped operands,
// B-frags direct from global, h in LDS. Grid 192, 4 waves x (64tok x 64feat).
// ---------------------------------------------------------------------------
__global__ __launch_bounds__(256) void oproj_k(const u16* __restrict__ O,
                                               const u16* __restrict__ wt1,
                                               const float* __restrict__ b1,
                                               const u16* __restrict__ wt2,
                                               const float* __restrict__ b2,
                                               float* __restrict__ out)
{
    __shared__ u16 Hs[128][136];   // [token][feature]

    const int tid  = threadIdx.x;
    const int wave = tid >> 6;
    const int lane = tid & 63;
    const int g    = lane >> 4;
    const int lc   = lane & 15;
    const int wr   = wave >> 1;
    const int wc   = wave & 1;
    const long mbase = (long)blockIdx.x * 128;

    const f32x4 ZERO4 = {0.f, 0.f, 0.f, 0.f};
    f32x4 acc[4][4];
#pragma unroll
    for (int m = 0; m < 4; ++m)
#pragma unroll
        for (int n = 0; n < 4; ++n) acc[m][n] = ZERO4;

    const u16* arow  = O   + (mbase + wr * 64 + lc) * 128;   // token frags
    const u16* b1row = wt1 + (wc * 64 + lc) * 128;           // feature frags
    const u16* b2row = wt2 + (wc * 64 + lc) * 128;

    // stage 1: h = relu(O*W1 + b1) -> Hs[tok][feat]
#pragma unroll 2
    for (int k0 = 0; k0 < 128; k0 += 32) {
        bf16x8 tf[4], wf[4];
#pragma unroll
        for (int m = 0; m < 4; ++m)
            tf[m] = *(const bf16x8*)(arow + m * 2048 + k0 + g * 8);
#pragma unroll
        for (int n = 0; n < 4; ++n)
            wf[n] = *(const bf16x8*)(b1row + n * 2048 + k0 + g * 8);
#pragma unroll
        for (int m = 0; m < 4; ++m)
#pragma unroll
            for (int n = 0; n < 4; ++n)
                acc[m][n] = mfma16(wf[n], tf[m], acc[m][n]);
    }
#pragma unroll
    for (int m = 0; m < 4; ++m) {
        const int tok = wr * 64 + m * 16 + lc;
#pragma unroll
        for (int n = 0; n < 4; ++n) {
            const int feat0 = wc * 64 + n * 16 + g * 4;
            f32x4 b4 = *(const f32x4*)(b1 + feat0);
            u16x4 pk;
#pragma unroll
            for (int r = 0; r < 4; ++r)
                pk[r] = f2bf(fmaxf(acc[m][n][r] + b4[r], 0.f));
            *(u16x4*)&Hs[tok][feat0] = pk;
            acc[m][n] = ZERO4;
        }
    }
    __syncthreads();

    // stage 2: out = h*W2 + b2
#pragma unroll 2
    for (int k0 = 0; k0 < 128; k0 += 32) {
        bf16x8 tf[4], wf[4];
#pragma unroll
        for (int m = 0; m < 4; ++m)
            tf[m] = *(const bf16x8*)&Hs[wr * 64 + m * 16 + lc][k0 + g * 8];
#pragma unroll
        for (int n = 0; n < 4; ++n)
            wf[n] = *(const bf16x8*)(b2row + n * 2048 + k0 + g * 8);
#pragma unroll
        for (int m = 0; m < 4; ++m)
#pragma unroll
            for (int n = 0; n < 4; ++n)
                acc[m][n] = mfma16(wf[n], tf[m], acc[m][n]);
    }
#pragma unroll
    for (int m = 0; m < 4; ++m) {
        const long tok = mbase + wr * 64 + m * 16 + lc;
#pragma unroll
        for (int n = 0; n < 4; ++n) {
            const int feat0 = wc * 64 + n * 16 + g * 4;
            f32x4 b4 = *(const f32x4*)(b2 + feat0);
            f32x4 v;
#pragma unroll
            for (int r = 0; r < 4; ++r) v[r] = acc[m][n][r] + b4[r];
            *(f32x4*)&out[tok * 128 + feat0] = v;
        }
    }
}

extern "C" void kernel_launch(void* const* d_in, const int* in_sizes, int n_in,
                              void* d_out, int out_size, void* d_ws, size_t ws_size,
                              hipStream_t stream)
{
    const float* x   = (const float*)d_in[0];
    const float* ste = (const float*)d_in[1];
    const float* Wq  = (const float*)d_in[2];
    const float* bq  = (const float*)d_in[3];
    const float* Wk  = (const float*)d_in[4];
    const float* bk  = (const float*)d_in[5];
    const float* Wv  = (const float*)d_in[6];
    const float* bv  = (const float*)d_in[7];
    const float* Wo1 = (const float*)d_in[8];
    const float* bo1 = (const float*)d_in[9];
    const float* Wo2 = (const float*)d_in[10];
    const float* bo2 = (const float*)d_in[11];
    float* out = (float*)d_out;

    const long MTOT = 24576;
    u16* xc   = (u16*)d_ws;                  // [24576][256] bf16
    u16* qbuf = xc + MTOT * 256;             // [384][512][16]
    u16* kbuf = qbuf + MTOT * 128;
    u16* vbuf = kbuf + MTOT * 128;           // V^T [384][16][512]
    u16* wtq  = vbuf + MTOT * 128;           // W^T bf16: [3][128][256]
    u16* wto1 = wtq + 3 * 32768;             // [2][128][128]
    u16* obuf = xc;                          // reuse xc after QKV

    const float QSCALE = 0.25f * 1.44269504f;   // 1/sqrt(16) * log2(e)

    dim3 blk(256);
    cvt_k<<<dim3(1664), blk, 0, stream>>>(x, ste, Wq, Wk, Wv, Wo1, Wo2, xc, wtq, wto1);
    qkv_k<<<dim3(192, 3), blk, 0, stream>>>(xc, wtq, bq, bk, bv, qbuf, kbuf, vbuf, QSCALE);
    attn_k<<<dim3(2, 8, 48), blk, 0, stream>>>(qbuf, kbuf, vbuf, obuf);
    oproj_k<<<dim3(192), blk, 0, stream>>>(obuf, wto1, bo1, wto1 + 16384, bo2, out);
}

// Round 11
// 84.162 us; speedup vs baseline: 1.0856x; 1.0097x over previous
//
#include <hip/hip_runtime.h>

// SpatialAttention: B=4 T=12 N=512 D=128, 8 heads x d=16.
// R5-champion pipeline byte-exact except oproj retile:
// cvt_k (R5 4-elem) -> qkv_k (LDS-free swapped GEMM from xc) ->
// attn_k (R5 flash, FROZEN 5/5) -> oproj_k (fused 2-stage, 96-token/256-block).

typedef unsigned short u16;
typedef unsigned int u32;
typedef __bf16 bf16_t;
typedef bf16_t bf16x8 __attribute__((ext_vector_type(8)));
typedef float f32x4 __attribute__((ext_vector_type(4)));
typedef u16 u16x8 __attribute__((ext_vector_type(8)));
typedef u16 u16x4 __attribute__((ext_vector_type(4)));
typedef u32 u32x2 __attribute__((ext_vector_type(2)));

__device__ __forceinline__ u16 f2bf(float f) {
    unsigned u = __builtin_bit_cast(unsigned, f);
    u += 0x7FFFu + ((u >> 16) & 1u);   // round-to-nearest-even
    return (u16)(u >> 16);
}

__device__ __forceinline__ f32x4 mfma16(bf16x8 a, bf16x8 b, f32x4 c) {
    return __builtin_amdgcn_mfma_f32_16x16x32_bf16(a, b, c, 0, 0, 0);
}

__device__ __forceinline__ u32 cvt_pk_bf16(float lo, float hi) {
    u32 w;
    asm("v_cvt_pk_bf16_f32 %0, %1, %2" : "=v"(w) : "v"(lo), "v"(hi));
    return w;
}

// ---------------------------------------------------------------------------
// Blocks 0..3071: xc[24576][256] = [bf16(x) | bf16(ste)]  (R5-exact)
// Blocks 3072..3199: weight transpose+convert: wt[3][128][256], wto[2][128][128]
// ---------------------------------------------------------------------------
__global__ __launch_bounds__(256) void cvt_k(const float* __restrict__ x,
                                             const float* __restrict__ ste,
                                             const float* __restrict__ Wq,
                                             const float* __restrict__ Wk,
                                             const float* __restrict__ Wv,
                                             const float* __restrict__ Wo1,
                                             const float* __restrict__ Wo2,
                                             u16* __restrict__ xc,
                                             u16* __restrict__ wtq,
                                             u16* __restrict__ wto1)
{
    const int b = blockIdx.x, tid = threadIdx.x;
    if (b < 3072) {
        long idx = (long)b * 256 + tid;
        long row = idx >> 5; int c = (int)(idx & 31);
        f32x4 a = *(const f32x4*)(x + idx * 4);
        f32x4 s = *(const f32x4*)(ste + idx * 4);
        u16x4 ha, hs;
#pragma unroll
        for (int j = 0; j < 4; ++j) { ha[j] = f2bf(a[j]); hs[j] = f2bf(s[j]); }
        *(u16x4*)(xc + row * 256 + c * 4)       = ha;
        *(u16x4*)(xc + row * 256 + 128 + c * 4) = hs;
    } else {
        int wb = b - 3072;
        const float* src; u16* dst; int K, lb;
        if (wb < 96) { int m = wb >> 5; src = (m == 0) ? Wq : (m == 1) ? Wk : Wv;
                       dst = wtq + m * 32768; K = 256; lb = wb & 31; }
        else         { int m = (wb - 96) >> 4; src = (m == 0) ? Wo1 : Wo2;
                       dst = wto1 + m * 16384; K = 128; lb = (wb - 96) & 15; }
        int pos = lb * 256 + tid;
        f32x4 v = *(const f32x4*)(src + (long)pos * 4);
        int k  = pos >> 5;
        int n0 = (pos * 4) & 127;
#pragma unroll
        for (int j = 0; j < 4; ++j) dst[(n0 + j) * K + k] = f2bf(v[j]);
    }
}

// ---------------------------------------------------------------------------
// LDS-free QKV projection, swapped operands: D[feature][token]. From xc (bf16).
// Grid (192,3): y=0 Q(scaled), y=1 K, y=2 V(V^T out). No LDS, no barriers.
// ---------------------------------------------------------------------------
__global__ __launch_bounds__(256) void qkv_k(const u16* __restrict__ xc,
                                             const u16* __restrict__ wt,
                                             const float* __restrict__ bq,
                                             const float* __restrict__ bk,
                                             const float* __restrict__ bv,
                                             u16* __restrict__ qbuf,
                                             u16* __restrict__ kbuf,
                                             u16* __restrict__ vbuf,
                                             float qscale)
{
    const int y = blockIdx.y;
    const u16* WT     = wt + y * 32768;                 // [128 feat][256 k]
    const float* bias = (y == 0) ? bq : (y == 1) ? bk : bv;
    u16* Out          = (y == 0) ? qbuf : (y == 1) ? kbuf : vbuf;
    const float scale = (y == 0) ? qscale : 1.0f;

    const int tid  = threadIdx.x;
    const int wave = tid >> 6;
    const int lane = tid & 63;
    const int g    = lane >> 4;
    const int lc   = lane & 15;
    const int wr   = wave >> 1;
    const int wc   = wave & 1;
    const long mbase = (long)blockIdx.x * 128;

    const u16* arow = xc + (mbase + wr * 64 + lc) * 256;   // token frags (B operand)
    const u16* brow = WT + (wc * 64 + lc) * 256;           // feature frags (A operand)

    const f32x4 ZERO4 = {0.f, 0.f, 0.f, 0.f};
    f32x4 acc[4][4];
#pragma unroll
    for (int m = 0; m < 4; ++m)
#pragma unroll
        for (int n = 0; n < 4; ++n) acc[m][n] = ZERO4;

#pragma unroll 2
    for (int k0 = 0; k0 < 256; k0 += 32) {
        bf16x8 tf[4], wf[4];
#pragma unroll
        for (int m = 0; m < 4; ++m)
            tf[m] = *(const bf16x8*)(arow + m * 4096 + k0 + g * 8);
#pragma unroll
        for (int n = 0; n < 4; ++n)
            wf[n] = *(const bf16x8*)(brow + n * 4096 + k0 + g * 8);
#pragma unroll
        for (int m = 0; m < 4; ++m)
#pragma unroll
            for (int n = 0; n < 4; ++n)
                acc[m][n] = mfma16(wf[n], tf[m], acc[m][n]);   // D[feat][tok]
    }

#pragma unroll
    for (int m = 0; m < 4; ++m) {
        const long tok = mbase + wr * 64 + m * 16 + lc;
        const long bt = tok >> 9;
        const long nn = tok & 511;
#pragma unroll
        for (int n = 0; n < 4; ++n) {
            const int feat0 = wc * 64 + n * 16 + g * 4;
            const int head  = feat0 >> 4;
            const int d0    = feat0 & 15;
            f32x4 b4 = *(const f32x4*)(bias + feat0);
            if (y == 2) {          // V^T: [head][16][512]
#pragma unroll
                for (int r = 0; r < 4; ++r) {
                    float v = fmaxf(acc[m][n][r] + b4[r], 0.f);
                    Out[((bt * 8 + head) * 16 + d0 + r) * 512 + nn] = f2bf(v);
                }
            } else {               // Q/K: [head][512][16], u16x4 fully coalesced
                u16x4 pk;
#pragma unroll
                for (int r = 0; r < 4; ++r)
                    pk[r] = f2bf(fmaxf(acc[m][n][r] + b4[r], 0.f) * scale);
                *(u16x4*)&Out[((bt * 8 + head) * 512 + nn) * 16 + d0] = pk;
            }
        }
    }
}

// ---------------------------------------------------------------------------
// Flash attention — R5-VALIDATED VERSION, FROZEN (passed 5/5). Swapped QK^T
// (S^T=mfma(K,Q)), lane owns one q-row; defer-max (THR=8 log2); cvt_pk P-pack;
// single per-wave Ps buffer; Ks+Vt staged in LDS. Grid (2,8,48), 4 waves.
// ---------------------------------------------------------------------------
__global__ __launch_bounds__(256) void attn_k(const u16* __restrict__ qb,
                                              const u16* __restrict__ kb,
                                              const u16* __restrict__ vtb,
                                              u16* __restrict__ ob)
{
    __shared__ u16 smem[25216];
    u16 (*Ks)[24]     = reinterpret_cast<u16(*)[24]>(smem);
    u16 (*Vt)[520]    = reinterpret_cast<u16(*)[520]>(smem + 12288);
    u16 (*Ps)[16][72] = reinterpret_cast<u16(*)[16][72]>(smem + 12288 + 8320);

    const int tid  = threadIdx.x;
    const int wave = tid >> 6;
    const int lane = tid & 63;
    const int g    = lane >> 4;
    const int lc   = lane & 15;
    const int qt = blockIdx.x, h = blockIdx.y, bt = blockIdx.z;
    const long hb = ((long)(bt * 8 + h)) * 8192;

    const u16x8 ZU8 = {0, 0, 0, 0, 0, 0, 0, 0};
    const bf16x8 zf = __builtin_bit_cast(bf16x8, ZU8);
    const f32x4 ZERO4 = {0.f, 0.f, 0.f, 0.f};

    // stage K [512][16]
#pragma unroll
    for (int i = 0; i < 4; ++i) {
        int pos = tid + i * 256;
        int row = pos >> 1, half = pos & 1;
        *(u16x8*)&Ks[row][half * 8] = *(const u16x8*)(kb + hb + row * 16 + half * 8);
    }
    // stage V^T [16][512]
#pragma unroll
    for (int i = 0; i < 4; ++i) {
        int pos = tid + i * 256;
        int r16 = pos >> 6, c8 = pos & 63;
        *(u16x8*)&Vt[r16][c8 * 8] = *(const u16x8*)(vtb + hb + r16 * 512 + c8 * 8);
    }

    const int qrow0 = qt * 256 + wave * 64;
    bf16x8 qf[4];
#pragma unroll
    for (int mt = 0; mt < 4; ++mt)
        qf[mt] = (g < 2) ? *(const bf16x8*)(qb + hb + (qrow0 + mt * 16 + lc) * 16 + g * 8) : zf;

    // per-lane state for q-row = (mt*16 + lc)
    float m_s[4], l_s[4];
    f32x4 oacc[4];
#pragma unroll
    for (int mt = 0; mt < 4; ++mt) { m_s[mt] = -1e30f; l_s[mt] = 0.f; oacc[mt] = ZERO4; }

    const int bcast = (lane & 48) + ((lane & 48) >> 2);   // src lane base for row g*4+r values

    __syncthreads();   // the only block-wide barrier

    for (int ch = 0; ch < 8; ++ch) {
        bf16x8 kf[4];
#pragma unroll
        for (int nt = 0; nt < 4; ++nt)
            kf[nt] = (g < 2) ? *(const bf16x8*)&Ks[ch * 64 + nt * 16 + lc][g * 8] : zf;

#pragma unroll
        for (int mt = 0; mt < 4; ++mt) {
            // S^T tiles: lane (lc,g) holds S[q=lc][key = ch*64 + nt*16 + g*4 + r]
            f32x4 st[4];
#pragma unroll
            for (int nt = 0; nt < 4; ++nt) st[nt] = mfma16(kf[nt], qf[mt], ZERO4);

            float mx = st[0][0];
#pragma unroll
            for (int nt = 0; nt < 4; ++nt)
#pragma unroll
                for (int r = 0; r < 4; ++r) mx = fmaxf(mx, st[nt][r]);
            mx = fmaxf(mx, __shfl_xor(mx, 16));
            mx = fmaxf(mx, __shfl_xor(mx, 32));

            float m0 = m_s[mt];
            if (__any(mx > m0 + 8.f)) {          // rescale path (rare after ch 0)
                float mnew = fmaxf(m0, mx);
                float alpha = __builtin_amdgcn_exp2f(m0 - mnew);
                f32x4 av;
#pragma unroll
                for (int r = 0; r < 4; ++r) av[r] = __shfl(alpha, bcast + r);
                oacc[mt] *= av;
                l_s[mt] *= alpha;
                m_s[mt] = mnew;
            }
            const float mm = m_s[mt];
            float rs = 0.f;
#pragma unroll
            for (int nt = 0; nt < 4; ++nt)
#pragma unroll
                for (int r = 0; r < 4; ++r) {
                    float p = __builtin_amdgcn_exp2f(st[nt][r] - mm);
                    st[nt][r] = p;
                    rs += p;
                }
            rs += __shfl_xor(rs, 16);
            rs += __shfl_xor(rs, 32);
            l_s[mt] += rs;

            // pack P -> bf16 pairs, b64 writes: Ps[wave][q=lc][key]
#pragma unroll
            for (int nt = 0; nt < 4; ++nt) {
                u32x2 w;
                w[0] = cvt_pk_bf16(st[nt][0], st[nt][1]);
                w[1] = cvt_pk_bf16(st[nt][2], st[nt][3]);
                *(u32x2*)&Ps[wave][lc][nt * 16 + g * 4] = w;
            }
            // O += P V
#pragma unroll
            for (int ks = 0; ks < 2; ++ks) {
                bf16x8 pf = *(const bf16x8*)&Ps[wave][lc][ks * 32 + g * 8];
                bf16x8 vf = *(const bf16x8*)&Vt[lc][ch * 64 + ks * 32 + g * 8];
                oacc[mt] = mfma16(pf, vf, oacc[mt]);
            }
        }
    }

    // write O [24576][128]; l for q-row g*4+r via shfl
#pragma unroll
    for (int mt = 0; mt < 4; ++mt)
#pragma unroll
        for (int r = 0; r < 4; ++r) {
            float lr = __shfl(l_s[mt], bcast + r);
            int row = qrow0 + mt * 16 + g * 4 + r;
            float rl = __builtin_amdgcn_rcpf(lr);
            ob[((long)bt * 512 + row) * 128 + h * 16 + lc] = f2bf(oacc[mt][r] * rl);
        }
}

// ---------------------------------------------------------------------------
// Fused output projections: out = relu(O*Wo1+bo1)*Wo2 + bo2. Swapped operands.
// 96-token tiles, grid 256 (exactly 1 block/CU — no idle CUs). 4 waves:
// wr-half owns 48 tokens (3 m-tiles), wc-half owns 64 feats. acc[3][4].
// ---------------------------------------------------------------------------
__global__ __launch_bounds__(256) void oproj_k(const u16* __restrict__ O,
                                               const u16* __restrict__ wt1,
                                               const float* __restrict__ b1,
                                               const u16* __restrict__ wt2,
                                               const float* __restrict__ b2,
                                               float* __restrict__ out)
{
    __shared__ u16 Hs[96][136];   // [token][feature]

    const int tid  = threadIdx.x;
    const int wave = tid >> 6;
    const int lane = tid & 63;
    const int g    = lane >> 4;
    const int lc   = lane & 15;
    const int wr   = wave >> 1;
    const int wc   = wave & 1;
    const long mbase = (long)blockIdx.x * 96;

    const f32x4 ZERO4 = {0.f, 0.f, 0.f, 0.f};
    f32x4 acc[3][4];
#pragma unroll
    for (int m = 0; m < 3; ++m)
#pragma unroll
        for (int n = 0; n < 4; ++n) acc[m][n] = ZERO4;

    const u16* arow  = O   + (mbase + wr * 48 + lc) * 128;   // token frags
    const u16* b1row = wt1 + (wc * 64 + lc) * 128;           // feature frags
    const u16* b2row = wt2 + (wc * 64 + lc) * 128;

    // stage 1: h = relu(O*W1 + b1) -> Hs[tok][feat]
#pragma unroll 2
    for (int k0 = 0; k0 < 128; k0 += 32) {
        bf16x8 tf[3], wf[4];
#pragma unroll
        for (int m = 0; m < 3; ++m)
            tf[m] = *(const bf16x8*)(arow + m * 2048 + k0 + g * 8);
#pragma unroll
        for (int n = 0; n < 4; ++n)
            wf[n] = *(const bf16x8*)(b1row + n * 2048 + k0 + g * 8);
#pragma unroll
        for (int m = 0; m < 3; ++m)
#pragma unroll
            for (int n = 0; n < 4; ++n)
                acc[m][n] = mfma16(wf[n], tf[m], acc[m][n]);
    }
#pragma unroll
    for (int m = 0; m < 3; ++m) {
        const int tok = wr * 48 + m * 16 + lc;
#pragma unroll
        for (int n = 0; n < 4; ++n) {
            const int feat0 = wc * 64 + n * 16 + g * 4;
            f32x4 b4 = *(const f32x4*)(b1 + feat0);
            u16x4 pk;
#pragma unroll
            for (int r = 0; r < 4; ++r)
                pk[r] = f2bf(fmaxf(acc[m][n][r] + b4[r], 0.f));
            *(u16x4*)&Hs[tok][feat0] = pk;
            acc[m][n] = ZERO4;
        }
    }
    __syncthreads();

    // stage 2: out = h*W2 + b2
#pragma unroll 2
    for (int k0 = 0; k0 < 128; k0 += 32) {
        bf16x8 tf[3], wf[4];
#pragma unroll
        for (int m = 0; m < 3; ++m)
            tf[m] = *(const bf16x8*)&Hs[wr * 48 + m * 16 + lc][k0 + g * 8];
#pragma unroll
        for (int n = 0; n < 4; ++n)
            wf[n] = *(const bf16x8*)(b2row + n * 2048 + k0 + g * 8);
#pragma unroll
        for (int m = 0; m < 3; ++m)
#pragma unroll
            for (int n = 0; n < 4; ++n)
                acc[m][n] = mfma16(wf[n], tf[m], acc[m][n]);
    }
#pragma unroll
    for (int m = 0; m < 3; ++m) {
        const long tok = mbase + wr * 48 + m * 16 + lc;
#pragma unroll
        for (int n = 0; n < 4; ++n) {
            const int feat0 = wc * 64 + n * 16 + g * 4;
            f32x4 b4 = *(const f32x4*)(b2 + feat0);
            f32x4 v;
#pragma unroll
            for (int r = 0; r < 4; ++r) v[r] = acc[m][n][r] + b4[r];
            *(f32x4*)&out[tok * 128 + feat0] = v;
        }
    }
}

extern "C" void kernel_launch(void* const* d_in, const int* in_sizes, int n_in,
                              void* d_out, int out_size, void* d_ws, size_t ws_size,
                              hipStream_t stream)
{
    const float* x   = (const float*)d_in[0];
    const float* ste = (const float*)d_in[1];
    const float* Wq  = (const float*)d_in[2];
    const float* bq  = (const float*)d_in[3];
    const float* Wk  = (const float*)d_in[4];
    const float* bk  = (const float*)d_in[5];
    const float* Wv  = (const float*)d_in[6];
    const float* bv  = (const float*)d_in[7];
    const float* Wo1 = (const float*)d_in[8];
    const float* bo1 = (const float*)d_in[9];
    const float* Wo2 = (const float*)d_in[10];
    const float* bo2 = (const float*)d_in[11];
    float* out = (float*)d_out;

    const long MTOT = 24576;
    u16* xc   = (u16*)d_ws;                  // [24576][256] bf16
    u16* qbuf = xc + MTOT * 256;             // [384][512][16]
    u16* kbuf = qbuf + MTOT * 128;
    u16* vbuf = kbuf + MTOT * 128;           // V^T [384][16][512]
    u16* wtq  = vbuf + MTOT * 128;           // W^T bf16: [3][128][256]
    u16* wto1 = wtq + 3 * 32768;             // [2][128][128]
    u16* obuf = xc;                          // reuse xc after QKV

    const float QSCALE = 0.25f * 1.44269504f;   // 1/sqrt(16) * log2(e)

    dim3 blk(256);
    cvt_k<<<dim3(3200), blk, 0, stream>>>(x, ste, Wq, Wk, Wv, Wo1, Wo2, xc, wtq, wto1);
    qkv_k<<<dim3(192, 3), blk, 0, stream>>>(xc, wtq, bq, bk, bv, qbuf, kbuf, vbuf, QSCALE);
    attn_k<<<dim3(2, 8, 48), blk, 0, stream>>>(qbuf, kbuf, vbuf, obuf);
    oproj_k<<<dim3(256), blk, 0, stream>>>(obuf, wto1, bo1, wto1 + 16384, bo2, out);
}